// Round 1
// baseline (375.142 us; speedup 1.0000x reference)
//
#include <hip/hip_runtime.h>
#include <hip/hip_bf16.h>

// Multihead cross-attention, B=2, LQ=LK=4096, D=768, H=8, dh=96.
// Pipeline: Wt transpose+bf16 -> QKV projection GEMMs (bf16 MFMA) -> flash attn.

typedef __bf16 bf16x8 __attribute__((ext_vector_type(8)));
typedef __bf16 bf16x4 __attribute__((ext_vector_type(4)));
typedef float  f32x4  __attribute__((ext_vector_type(4)));

#define DM   768
#define NH   8
#define HD   96
#define SEQ  4096
#define BATCH 2
#define WELEM (DM*DM)   // 589824

// ---------------- W transpose + f32->bf16 (one launch, 3 matrices) -------------
__global__ __launch_bounds__(256) void transpose_w3(
    const float* __restrict__ Wq, const float* __restrict__ Wk, const float* __restrict__ Wv,
    __bf16* __restrict__ Tq, __bf16* __restrict__ Tk, __bf16* __restrict__ Tv)
{
    int tid = blockIdx.x * 256 + threadIdx.x;   // 3*589824 total
    int which = tid / WELEM;                    // uniform per block (2304 blocks each)
    int e = tid - which * WELEM;
    int k = e / DM, n = e - k * DM;             // W[k][n], read coalesced
    const float* W = (which == 0) ? Wq : (which == 1) ? Wk : Wv;
    __bf16* T      = (which == 0) ? Tq : (which == 1) ? Tk : Tv;
    T[n * DM + k] = (__bf16)W[e];
}

// ---------------- projection GEMM: Y = X @ W  (X f32 [8192][768], Wt bf16 [n][k]) ----
// mode 0: Y[b][h][l][d] = acc*scale   (Q: scale=log2e/sqrt(96); K: scale=1)
// mode 1: Y[b][h][d][l] = acc         (V transposed)
__global__ __launch_bounds__(256) void proj_gemm(
    const float* __restrict__ X, const __bf16* __restrict__ Wt,
    __bf16* __restrict__ Y, int mode, float scale)
{
    __shared__ __bf16 Xs[64][40];   // +8 pad: row stride 80B -> 2-way max bank pattern
    __shared__ __bf16 Ws[64][40];

    const int t = threadIdx.x;
    const int l = t & 63;
    const int w = t >> 6;
    const int wm = w >> 1, wn = w & 1;
    const int m0 = blockIdx.x * 64;
    const int n0 = blockIdx.y * 64;

    const int srow = t >> 2;
    const int scol = (t & 3) * 8;

    f32x4 acc[2][2] = {};

    for (int kt = 0; kt < DM / 32; ++kt) {
        const int k0 = kt * 32;
        __syncthreads();
        {   // stage X tile 64x32 (f32 -> bf16)
            const float* src = X + (size_t)(m0 + srow) * DM + k0 + scol;
            float4 lo = *reinterpret_cast<const float4*>(src);
            float4 hi = *reinterpret_cast<const float4*>(src + 4);
            bf16x8 v;
            v[0]=(__bf16)lo.x; v[1]=(__bf16)lo.y; v[2]=(__bf16)lo.z; v[3]=(__bf16)lo.w;
            v[4]=(__bf16)hi.x; v[5]=(__bf16)hi.y; v[6]=(__bf16)hi.z; v[7]=(__bf16)hi.w;
            *reinterpret_cast<bf16x8*>(&Xs[srow][scol]) = v;
        }
        {   // stage Wt tile 64(n)x32(k), already bf16
            const __bf16* src = Wt + (size_t)(n0 + srow) * DM + k0 + scol;
            *reinterpret_cast<bf16x8*>(&Ws[srow][scol]) =
                *reinterpret_cast<const bf16x8*>(src);
        }
        __syncthreads();

        bf16x8 a[2], b[2];
        #pragma unroll
        for (int ms = 0; ms < 2; ++ms)
            a[ms] = *reinterpret_cast<const bf16x8*>(&Xs[wm*32 + ms*16 + (l & 15)][(l >> 4) * 8]);
        #pragma unroll
        for (int ns = 0; ns < 2; ++ns)
            b[ns] = *reinterpret_cast<const bf16x8*>(&Ws[wn*32 + ns*16 + (l & 15)][(l >> 4) * 8]);
        #pragma unroll
        for (int ms = 0; ms < 2; ++ms)
            #pragma unroll
            for (int ns = 0; ns < 2; ++ns)
                acc[ms][ns] = __builtin_amdgcn_mfma_f32_16x16x32_bf16(a[ms], b[ns], acc[ms][ns], 0, 0, 0);
    }

    // epilogue: D layout col=lane&15, row=4*(lane>>4)+r  [m89]
    #pragma unroll
    for (int ms = 0; ms < 2; ++ms) {
        #pragma unroll
        for (int ns = 0; ns < 2; ++ns) {
            const int col = n0 + wn*32 + ns*16 + (l & 15);
            const int h = col / HD, d = col - h * HD;
            const int row_base = m0 + wm*32 + ms*16 + (l >> 4) * 4;
            if (mode == 0) {
                #pragma unroll
                for (int r = 0; r < 4; ++r) {
                    int row = row_base + r;
                    int b_ = row >> 12, q = row & (SEQ - 1);
                    Y[(((size_t)(b_ * NH + h) * SEQ) + q) * HD + d] =
                        (__bf16)(acc[ms][ns][r] * scale);
                }
            } else {
                int b_ = row_base >> 12, kq = row_base & (SEQ - 1);
                bf16x4 v;
                #pragma unroll
                for (int r = 0; r < 4; ++r) v[r] = (__bf16)acc[ms][ns][r];
                *reinterpret_cast<bf16x4*>(
                    &Y[((size_t)(b_ * NH + h) * HD + d) * SEQ + kq]) = v;
            }
        }
    }
}

// ---------------- flash attention ----------------
// grid (LQ/64, B*H), 4 waves x 16 q-rows, KBLK=64. Q prescaled by log2e/sqrt(96).
__global__ __launch_bounds__(256) void attn_kernel(
    const __bf16* __restrict__ Q, const __bf16* __restrict__ K,
    const __bf16* __restrict__ Vt, float* __restrict__ out)
{
    __shared__ __bf16 Ks[64][104];    // K tile  [k][d], pad +8
    __shared__ __bf16 Vs[96][72];     // Vt tile [d][k], pad +8
    __shared__ __bf16 Ps[4][16][72];  // per-wave P tile [q][k], pad +8

    const int t = threadIdx.x;
    const int l = t & 63;
    const int w = t >> 6;
    const int g = l >> 4;            // 16-lane group id
    const int ln = l & 15;
    const int bh = blockIdx.y;
    const int b = bh >> 3, h = bh & 7;
    const int q0 = blockIdx.x * 64;

    const size_t base = (size_t)bh * SEQ * HD;   // same constant for Q,K,Vt layouts
    const __bf16* Kg = K + base;
    const __bf16* Vg = Vt + base;

    // Q fragments (A-operand: row=lane&15, k=8*(lane>>4)+e), held in registers
    bf16x8 qf[3];
    const int qrow = q0 + w * 16 + ln;
    #pragma unroll
    for (int c = 0; c < 3; ++c)
        qf[c] = *reinterpret_cast<const bf16x8*>(&Q[base + (size_t)qrow * HD + c * 32 + g * 8]);

    f32x4 acc[6] = {};
    float m_r[4], l_r[4];
    #pragma unroll
    for (int r = 0; r < 4; ++r) { m_r[r] = -1e30f; l_r[r] = 0.f; }

    for (int kt = 0; kt < SEQ / 64; ++kt) {
        const int k0 = kt * 64;
        __syncthreads();
        // stage K tile 64x96: 768 vec8 chunks
        #pragma unroll
        for (int it = 0; it < 3; ++it) {
            int idx = t + it * 256;
            int row = idx / 12, c = (idx % 12) * 8;
            *reinterpret_cast<bf16x8*>(&Ks[row][c]) =
                *reinterpret_cast<const bf16x8*>(&Kg[(size_t)(k0 + row) * HD + c]);
        }
        // stage Vt tile 96x64
        #pragma unroll
        for (int it = 0; it < 3; ++it) {
            int idx = t + it * 256;
            int row = idx >> 3, c = (idx & 7) * 8;
            *reinterpret_cast<bf16x8*>(&Vs[row][c]) =
                *reinterpret_cast<const bf16x8*>(&Vg[(size_t)row * SEQ + k0 + c]);
        }
        __syncthreads();

        // S = Q K^T : 16 q-rows x 64 k-cols per wave (4 ksub x 3 d-chunks)
        f32x4 s[4];
        #pragma unroll
        for (int ks = 0; ks < 4; ++ks) {
            f32x4 a = {};
            #pragma unroll
            for (int c = 0; c < 3; ++c) {
                bf16x8 kf = *reinterpret_cast<const bf16x8*>(
                    &Ks[ks * 16 + ln][c * 32 + g * 8]);
                a = __builtin_amdgcn_mfma_f32_16x16x32_bf16(qf[c], kf, a, 0, 0, 0);
            }
            s[ks] = a;
        }

        // online softmax (all in exp2 domain; log2e folded into Q scale)
        float mnew[4], alpha[4], psum[4];
        #pragma unroll
        for (int r = 0; r < 4; ++r) {
            float v = fmaxf(fmaxf(s[0][r], s[1][r]), fmaxf(s[2][r], s[3][r]));
            #pragma unroll
            for (int mk = 1; mk < 16; mk <<= 1)
                v = fmaxf(v, __shfl_xor(v, mk, 64));
            mnew[r] = fmaxf(m_r[r], v);
            alpha[r] = __builtin_amdgcn_exp2f(m_r[r] - mnew[r]);
            m_r[r] = mnew[r];
            psum[r] = 0.f;
        }
        #pragma unroll
        for (int ks = 0; ks < 4; ++ks) {
            #pragma unroll
            for (int r = 0; r < 4; ++r) {
                float p = __builtin_amdgcn_exp2f(s[ks][r] - mnew[r]);
                psum[r] += p;
                Ps[w][g * 4 + r][ks * 16 + ln] = (__bf16)p;   // D-layout -> LDS
            }
        }
        #pragma unroll
        for (int r = 0; r < 4; ++r) {
            float v = psum[r];
            #pragma unroll
            for (int mk = 1; mk < 16; mk <<= 1)
                v += __shfl_xor(v, mk, 64);
            l_r[r] = l_r[r] * alpha[r] + v;
        }
        #pragma unroll
        for (int ns = 0; ns < 6; ++ns)
            #pragma unroll
            for (int r = 0; r < 4; ++r)
                acc[ns][r] *= alpha[r];

        // PV: ctx += P[16x64] @ V[64x96]
        #pragma unroll
        for (int kc = 0; kc < 2; ++kc) {
            bf16x8 pa = *reinterpret_cast<const bf16x8*>(&Ps[w][ln][kc * 32 + g * 8]);
            #pragma unroll
            for (int ns = 0; ns < 6; ++ns) {
                bf16x8 vf = *reinterpret_cast<const bf16x8*>(
                    &Vs[ns * 16 + ln][kc * 32 + g * 8]);
                acc[ns] = __builtin_amdgcn_mfma_f32_16x16x32_bf16(pa, vf, acc[ns], 0, 0, 0);
            }
        }
    }

    // normalize + write: out[b][q][h*96+d] f32
    #pragma unroll
    for (int r = 0; r < 4; ++r) {
        float inv = 1.0f / l_r[r];
        int q = q0 + w * 16 + g * 4 + r;
        float* dst = out + ((size_t)(b * SEQ + q)) * DM + h * HD;
        #pragma unroll
        for (int ns = 0; ns < 6; ++ns)
            dst[ns * 16 + ln] = acc[ns][r] * inv;
    }
}

extern "C" void kernel_launch(void* const* d_in, const int* in_sizes, int n_in,
                              void* d_out, int out_size, void* d_ws, size_t ws_size,
                              hipStream_t stream) {
    const float* hidden = (const float*)d_in[0];
    const float* kv     = (const float*)d_in[1];
    const float* Wq     = (const float*)d_in[2];
    const float* Wk     = (const float*)d_in[3];
    const float* Wv     = (const float*)d_in[4];
    float* out = (float*)d_out;

    // workspace layout (bf16): Wt_q, Wt_k, Wt_v, Q, K, Vt  (~41.3 MB total)
    __bf16* Wt_q = (__bf16*)d_ws;
    __bf16* Wt_k = Wt_q + WELEM;
    __bf16* Wt_v = Wt_k + WELEM;
    __bf16* Qb   = Wt_v + WELEM;
    __bf16* Kb   = Qb + (size_t)BATCH * NH * SEQ * HD;
    __bf16* Vtb  = Kb + (size_t)BATCH * NH * SEQ * HD;

    transpose_w3<<<3 * (WELEM / 256), 256, 0, stream>>>(Wq, Wk, Wv, Wt_q, Wt_k, Wt_v);

    const float qscale = 0.10206207261596575f * 1.4426950408889634f; // 1/sqrt(96)*log2(e)
    dim3 pgrid(BATCH * SEQ / 64, DM / 64);
    proj_gemm<<<pgrid, 256, 0, stream>>>(hidden, Wt_q, Qb, 0, qscale);
    proj_gemm<<<pgrid, 256, 0, stream>>>(kv,     Wt_k, Kb, 0, 1.0f);
    proj_gemm<<<pgrid, 256, 0, stream>>>(kv,     Wt_v, Vtb, 1, 1.0f);

    attn_kernel<<<dim3(SEQ / 64, BATCH * NH), 256, 0, stream>>>(Qb, Kb, Vtb, out);
}

// Round 2
// 246.924 us; speedup vs baseline: 1.5193x; 1.5193x over previous
//
#include <hip/hip_runtime.h>
#include <hip/hip_bf16.h>

// Multihead cross-attention, B=2, LQ=LK=4096, D=768, H=8, dh=96.
// Pipeline: Wt transpose+bf16 -> QKV projection GEMMs (bf16 MFMA) -> flash attn.
// Attn: swapped-QK^T (S^T, q lane-local softmax), 32 q/wave, KBLK=64,
//       double-buffered reg staging, defer-rescale.

typedef __bf16 bf16x8 __attribute__((ext_vector_type(8)));
typedef __bf16 bf16x4 __attribute__((ext_vector_type(4)));
typedef float  f32x4  __attribute__((ext_vector_type(4)));

#define DM   768
#define NH   8
#define HD   96
#define SEQ  4096
#define BATCH 2
#define WELEM (DM*DM)   // 589824

// ---------------- W transpose + f32->bf16 (one launch, 3 matrices) -------------
__global__ __launch_bounds__(256) void transpose_w3(
    const float* __restrict__ Wq, const float* __restrict__ Wk, const float* __restrict__ Wv,
    __bf16* __restrict__ Tq, __bf16* __restrict__ Tk, __bf16* __restrict__ Tv)
{
    int tid = blockIdx.x * 256 + threadIdx.x;   // 3*589824 total
    int which = tid / WELEM;                    // uniform per block (2304 blocks each)
    int e = tid - which * WELEM;
    int k = e / DM, n = e - k * DM;             // W[k][n], read coalesced
    const float* W = (which == 0) ? Wq : (which == 1) ? Wk : Wv;
    __bf16* T      = (which == 0) ? Tq : (which == 1) ? Tk : Tv;
    T[n * DM + k] = (__bf16)W[e];
}

// ---------------- projection GEMM: Y = X @ W  (X f32 [8192][768], Wt bf16 [n][k]) ----
// mode 0: Y[b][h][l][d] = acc*scale   (Q: scale=log2e/sqrt(96); K: scale=1)
// mode 1: Y[b][h][d][l] = acc         (V transposed)
__global__ __launch_bounds__(256) void proj_gemm(
    const float* __restrict__ X, const __bf16* __restrict__ Wt,
    __bf16* __restrict__ Y, int mode, float scale)
{
    __shared__ __bf16 Xs[64][40];   // +8 pad: row stride 80B -> 2-way max bank pattern
    __shared__ __bf16 Ws[64][40];

    const int t = threadIdx.x;
    const int l = t & 63;
    const int w = t >> 6;
    const int wm = w >> 1, wn = w & 1;
    const int m0 = blockIdx.x * 64;
    const int n0 = blockIdx.y * 64;

    const int srow = t >> 2;
    const int scol = (t & 3) * 8;

    f32x4 acc[2][2] = {};

    for (int kt = 0; kt < DM / 32; ++kt) {
        const int k0 = kt * 32;
        __syncthreads();
        {   // stage X tile 64x32 (f32 -> bf16)
            const float* src = X + (size_t)(m0 + srow) * DM + k0 + scol;
            float4 lo = *reinterpret_cast<const float4*>(src);
            float4 hi = *reinterpret_cast<const float4*>(src + 4);
            bf16x8 v;
            v[0]=(__bf16)lo.x; v[1]=(__bf16)lo.y; v[2]=(__bf16)lo.z; v[3]=(__bf16)lo.w;
            v[4]=(__bf16)hi.x; v[5]=(__bf16)hi.y; v[6]=(__bf16)hi.z; v[7]=(__bf16)hi.w;
            *reinterpret_cast<bf16x8*>(&Xs[srow][scol]) = v;
        }
        {   // stage Wt tile 64(n)x32(k), already bf16
            const __bf16* src = Wt + (size_t)(n0 + srow) * DM + k0 + scol;
            *reinterpret_cast<bf16x8*>(&Ws[srow][scol]) =
                *reinterpret_cast<const bf16x8*>(src);
        }
        __syncthreads();

        bf16x8 a[2], b[2];
        #pragma unroll
        for (int ms = 0; ms < 2; ++ms)
            a[ms] = *reinterpret_cast<const bf16x8*>(&Xs[wm*32 + ms*16 + (l & 15)][(l >> 4) * 8]);
        #pragma unroll
        for (int ns = 0; ns < 2; ++ns)
            b[ns] = *reinterpret_cast<const bf16x8*>(&Ws[wn*32 + ns*16 + (l & 15)][(l >> 4) * 8]);
        #pragma unroll
        for (int ms = 0; ms < 2; ++ms)
            #pragma unroll
            for (int ns = 0; ns < 2; ++ns)
                acc[ms][ns] = __builtin_amdgcn_mfma_f32_16x16x32_bf16(a[ms], b[ns], acc[ms][ns], 0, 0, 0);
    }

    // epilogue: D layout col=lane&15, row=4*(lane>>4)+r  [m89]
    #pragma unroll
    for (int ms = 0; ms < 2; ++ms) {
        #pragma unroll
        for (int ns = 0; ns < 2; ++ns) {
            const int col = n0 + wn*32 + ns*16 + (l & 15);
            const int h = col / HD, d = col - h * HD;
            const int row_base = m0 + wm*32 + ms*16 + (l >> 4) * 4;
            if (mode == 0) {
                #pragma unroll
                for (int r = 0; r < 4; ++r) {
                    int row = row_base + r;
                    int b_ = row >> 12, q = row & (SEQ - 1);
                    Y[(((size_t)(b_ * NH + h) * SEQ) + q) * HD + d] =
                        (__bf16)(acc[ms][ns][r] * scale);
                }
            } else {
                int b_ = row_base >> 12, kq = row_base & (SEQ - 1);
                bf16x4 v;
                #pragma unroll
                for (int r = 0; r < 4; ++r) v[r] = (__bf16)acc[ms][ns][r];
                *reinterpret_cast<bf16x4*>(
                    &Y[((size_t)(b_ * NH + h) * HD + d) * SEQ + kq]) = v;
            }
        }
    }
}

// ---------------- flash attention (swapped QK^T) ----------------
// grid (LQ/128, B*H), 4 waves x 32 q-rows, KBLK=64, double-buffered staging.
// Q prescaled by log2e/sqrt(96). S^T layout: lane holds S[k=16ks+4g+r][q=ln+16f].
__global__ __launch_bounds__(256) void attn_kernel(
    const __bf16* __restrict__ Q, const __bf16* __restrict__ K,
    const __bf16* __restrict__ Vt, float* __restrict__ out)
{
    __shared__ __bf16 Ks[2][64][104];   // K tile [k][d], stride 208B = 13 quads (2-way max)
    __shared__ __bf16 Vs[2][96][72];    // Vt tile [d][k], stride 144B = 9 quads (2-way max)
    __shared__ __bf16 Pl[4][32][40];    // per-wave P [q][k32], stride 80B = 5 quads (2-way max)

    const int t = threadIdx.x;
    const int l = t & 63;
    const int w = t >> 6;
    const int g = l >> 4;            // 16-lane group id (0..3)
    const int ln = l & 15;
    const int bh = blockIdx.y;
    const int b = bh >> 3, h = bh & 7;
    const int q0 = blockIdx.x * 128;

    const size_t base = (size_t)bh * SEQ * HD;
    const __bf16* Kg = K + base;
    const __bf16* Vg = Vt + base;

    // per-thread staging geometry (constant across ktiles)
    int kro[3], krw[3], kcl[3], vro[3], vrw[3], vcl[3];
    #pragma unroll
    for (int i = 0; i < 3; ++i) {
        int idx = t + 256 * i;               // 0..767  K chunks
        krw[i] = idx / 12; kcl[i] = (idx - krw[i] * 12) * 8;
        kro[i] = krw[i] * HD + kcl[i];
        int j = t + 256 * i;                 // 0..767  V chunks
        vrw[i] = j >> 3; vcl[i] = (j & 7) * 8;
        vro[i] = vrw[i] * SEQ + vcl[i];
    }

    // Q B-fragments in registers: B-frag n=ln, k=8g+e
    bf16x8 qb[2][3];
    #pragma unroll
    for (int f = 0; f < 2; ++f) {
        const int q = q0 + w * 32 + 16 * f + ln;
        #pragma unroll
        for (int c = 0; c < 3; ++c)
            qb[f][c] = *reinterpret_cast<const bf16x8*>(
                &Q[base + (size_t)q * HD + c * 32 + g * 8]);
    }

    f32x4 acc[2][6] = {};
    float m0r = -1e30f, m1r = -1e30f, l0r = 0.f, l1r = 0.f;

    // prologue: stage tile 0 -> buf 0
    {
        bf16x8 pf[6];
        #pragma unroll
        for (int i = 0; i < 3; ++i) pf[i]   = *reinterpret_cast<const bf16x8*>(Kg + kro[i]);
        #pragma unroll
        for (int i = 0; i < 3; ++i) pf[3+i] = *reinterpret_cast<const bf16x8*>(Vg + vro[i]);
        #pragma unroll
        for (int i = 0; i < 3; ++i) *reinterpret_cast<bf16x8*>(&Ks[0][krw[i]][kcl[i]]) = pf[i];
        #pragma unroll
        for (int i = 0; i < 3; ++i) *reinterpret_cast<bf16x8*>(&Vs[0][vrw[i]][vcl[i]]) = pf[3+i];
    }
    __syncthreads();

    for (int kt = 0; kt < SEQ / 64; ++kt) {
        const int cur = kt & 1;
        const bool more = kt < SEQ / 64 - 1;

        // issue prefetch loads EARLY (latency hides under compute)
        bf16x8 pf[6];
        if (more) {
            const size_t k0n = (size_t)(kt + 1) * 64;
            #pragma unroll
            for (int i = 0; i < 3; ++i)
                pf[i]   = *reinterpret_cast<const bf16x8*>(Kg + k0n * HD + kro[i]);
            #pragma unroll
            for (int i = 0; i < 3; ++i)
                pf[3+i] = *reinterpret_cast<const bf16x8*>(Vg + k0n + vro[i]);
        }

        // ---- QK^T: S^T[k][q], A=K(m=k), B=Q(n=q) ----
        f32x4 s[2][4] = {};
        #pragma unroll
        for (int ks = 0; ks < 4; ++ks) {
            bf16x8 ka[3];
            #pragma unroll
            for (int c = 0; c < 3; ++c)
                ka[c] = *reinterpret_cast<const bf16x8*>(
                    &Ks[cur][ks * 16 + ln][c * 32 + g * 8]);
            #pragma unroll
            for (int f = 0; f < 2; ++f)
                #pragma unroll
                for (int c = 0; c < 3; ++c)
                    s[f][ks] = __builtin_amdgcn_mfma_f32_16x16x32_bf16(
                        ka[c], qb[f][c], s[f][ks], 0, 0, 0);
        }

        // ---- online softmax: q lane-local (q = ln + 16f), replicated over g ----
        float tm[2];
        #pragma unroll
        for (int f = 0; f < 2; ++f) {
            float v = s[f][0][0];
            #pragma unroll
            for (int ks = 0; ks < 4; ++ks)
                #pragma unroll
                for (int r = 0; r < 4; ++r) v = fmaxf(v, s[f][ks][r]);
            v = fmaxf(v, __shfl_xor(v, 16));
            v = fmaxf(v, __shfl_xor(v, 32));
            tm[f] = v;
        }
        if (__any((tm[0] > m0r) || (tm[1] > m1r))) {   // defer-rescale: rare after warmup
            float mn0 = fmaxf(m0r, tm[0]), mn1 = fmaxf(m1r, tm[1]);
            float a0 = __builtin_amdgcn_exp2f(m0r - mn0);
            float a1 = __builtin_amdgcn_exp2f(m1r - mn1);
            m0r = mn0; m1r = mn1;
            l0r *= a0; l1r *= a1;
            float ab0[4], ab1[4];
            #pragma unroll
            for (int r = 0; r < 4; ++r) {
                ab0[r] = __shfl(a0, g * 4 + r);   // alpha for q-local 4g+r
                ab1[r] = __shfl(a1, g * 4 + r);
            }
            #pragma unroll
            for (int ns = 0; ns < 6; ++ns)
                #pragma unroll
                for (int r = 0; r < 4; ++r) {
                    acc[0][ns][r] *= ab0[r];
                    acc[1][ns][r] *= ab1[r];
                }
        }
        // p = exp2(s - m) in place; row-sum
        #pragma unroll
        for (int f = 0; f < 2; ++f) {
            const float mm = f ? m1r : m0r;
            float ps = 0.f;
            #pragma unroll
            for (int ks = 0; ks < 4; ++ks)
                #pragma unroll
                for (int r = 0; r < 4; ++r) {
                    float p = __builtin_amdgcn_exp2f(s[f][ks][r] - mm);
                    s[f][ks][r] = p;
                    ps += p;
                }
            ps += __shfl_xor(ps, 16);
            ps += __shfl_xor(ps, 32);
            if (f) l1r += ps; else l0r += ps;
        }

        // ---- PV per 32-k chunk: P through per-wave LDS, A=P(m=q), B=V(n=d) ----
        #pragma unroll
        for (int kc = 0; kc < 2; ++kc) {
            #pragma unroll
            for (int f = 0; f < 2; ++f) {
                bf16x4 p0, p1;
                #pragma unroll
                for (int r = 0; r < 4; ++r) {
                    p0[r] = (__bf16)s[f][2 * kc][r];
                    p1[r] = (__bf16)s[f][2 * kc + 1][r];
                }
                *reinterpret_cast<bf16x4*>(&Pl[w][16 * f + ln][4 * g])      = p0;
                *reinterpret_cast<bf16x4*>(&Pl[w][16 * f + ln][16 + 4 * g]) = p1;
            }
            bf16x8 pa[2];
            #pragma unroll
            for (int f = 0; f < 2; ++f)
                pa[f] = *reinterpret_cast<const bf16x8*>(&Pl[w][16 * f + ln][8 * g]);
            #pragma unroll
            for (int ns = 0; ns < 6; ++ns) {
                bf16x8 vb = *reinterpret_cast<const bf16x8*>(
                    &Vs[cur][ns * 16 + ln][kc * 32 + 8 * g]);
                #pragma unroll
                for (int f = 0; f < 2; ++f)
                    acc[f][ns] = __builtin_amdgcn_mfma_f32_16x16x32_bf16(
                        pa[f], vb, acc[f][ns], 0, 0, 0);
            }
        }

        // write prefetched tile into the other buffer, then one barrier
        if (more) {
            const int nxt = cur ^ 1;
            #pragma unroll
            for (int i = 0; i < 3; ++i)
                *reinterpret_cast<bf16x8*>(&Ks[nxt][krw[i]][kcl[i]]) = pf[i];
            #pragma unroll
            for (int i = 0; i < 3; ++i)
                *reinterpret_cast<bf16x8*>(&Vs[nxt][vrw[i]][vcl[i]]) = pf[3+i];
        }
        __syncthreads();
    }

    // epilogue: acc layout col=ln=d, row=4g+r=q-local(16f+4g+r)
    #pragma unroll
    for (int f = 0; f < 2; ++f) {
        const float lf = f ? l1r : l0r;
        float inv[4];
        #pragma unroll
        for (int r = 0; r < 4; ++r)
            inv[r] = 1.0f / __shfl(lf, g * 4 + r);
        #pragma unroll
        for (int ns = 0; ns < 6; ++ns)
            #pragma unroll
            for (int r = 0; r < 4; ++r) {
                const int q = q0 + w * 32 + 16 * f + 4 * g + r;
                out[((size_t)(b * SEQ + q)) * DM + h * HD + ns * 16 + ln] =
                    acc[f][ns][r] * inv[r];
            }
    }
}

extern "C" void kernel_launch(void* const* d_in, const int* in_sizes, int n_in,
                              void* d_out, int out_size, void* d_ws, size_t ws_size,
                              hipStream_t stream) {
    const float* hidden = (const float*)d_in[0];
    const float* kv     = (const float*)d_in[1];
    const float* Wq     = (const float*)d_in[2];
    const float* Wk     = (const float*)d_in[3];
    const float* Wv     = (const float*)d_in[4];
    float* out = (float*)d_out;

    // workspace layout (bf16): Wt_q, Wt_k, Wt_v, Q, K, Vt  (~41.3 MB total)
    __bf16* Wt_q = (__bf16*)d_ws;
    __bf16* Wt_k = Wt_q + WELEM;
    __bf16* Wt_v = Wt_k + WELEM;
    __bf16* Qb   = Wt_v + WELEM;
    __bf16* Kb   = Qb + (size_t)BATCH * NH * SEQ * HD;
    __bf16* Vtb  = Kb + (size_t)BATCH * NH * SEQ * HD;

    transpose_w3<<<3 * (WELEM / 256), 256, 0, stream>>>(Wq, Wk, Wv, Wt_q, Wt_k, Wt_v);

    const float qscale = 0.10206207261596575f * 1.4426950408889634f; // 1/sqrt(96)*log2(e)
    dim3 pgrid(BATCH * SEQ / 64, DM / 64);
    proj_gemm<<<pgrid, 256, 0, stream>>>(hidden, Wt_q, Qb, 0, qscale);
    proj_gemm<<<pgrid, 256, 0, stream>>>(kv,     Wt_k, Kb, 0, 1.0f);
    proj_gemm<<<pgrid, 256, 0, stream>>>(kv,     Wt_v, Vtb, 1, 1.0f);

    attn_kernel<<<dim3(SEQ / 128, BATCH * NH), 256, 0, stream>>>(Qb, Kb, Vtb, out);
}